// Round 4
// baseline (166.634 us; speedup 1.0000x reference)
//
#include <hip/hip_runtime.h>
#include <hip/hip_bf16.h>

// MultiHeadLiftLayer:
//   y0 = x0 @ W[:128]  (per-node, 50000x8)   -> table in d_ws
//   y1 = x0 @ W[128:]  (per-node, 50000x8)   -> table in d_ws (offset)
//   out[e, 0:8]  = relu(y0[src[e]] + y1[tgt[e]])
//   out[e, 8:72] = x_1[e]                     // (625000, 72) f32
//
// Kernel 2 uses ROLE-SPECIALIZED blocks: 7/8 of blocks are pure streaming
// copy waves (x1 -> out columns, memcpy-rate), 1/8 are gather/relu head
// waves. Both roles co-resident per CU so gather latency hides under the
// copy stream. All out stores are nontemporal: out is never re-read, and
// keeping it out of L3 leaves x1 (160 MB) resident across graph replays.

typedef float f4v __attribute__((ext_vector_type(4)));  // clang vector: ok for nt builtins

#define NUM_NODES 50000
#define C0 128
#define HEADS 8
#define NODES_PER_BLK 16
#define XS_STRIDE 132            // 128 + 4 pad
#define TOTAL_BLOCKS 2048        // 8 blocks/CU on 256 CUs
#define COPY_BLOCKS 1792
#define HEAD_BLOCKS 256

__global__ __launch_bounds__(256) void node_proj_kernel(
    const float* __restrict__ x0, const float* __restrict__ W,
    float* __restrict__ y, int num_nodes)
{
    __shared__ float Ws[2 * C0 * HEADS];          // 8 KB
    __shared__ float xs[NODES_PER_BLK * XS_STRIDE];

    for (int i = threadIdx.x; i < 2 * C0 * HEADS; i += 256) Ws[i] = W[i];

    const int nodeBase = blockIdx.x * NODES_PER_BLK;
    for (int i = threadIdx.x; i < NODES_PER_BLK * C0; i += 256) {
        int r = i >> 7;
        int c = i & (C0 - 1);
        int n = nodeBase + r;
        xs[r * XS_STRIDE + c] = (n < num_nodes) ? x0[n * C0 + c] : 0.f;
    }
    __syncthreads();

    const int local = threadIdx.x >> 4;
    const int slot  = threadIdx.x & 15;   // half*8 + h
    const int half  = slot >> 3;
    const int h     = slot & 7;

    const float* xr = &xs[local * XS_STRIDE];
    const float* Wr = &Ws[half * C0 * HEADS + h];

    float acc = 0.f;
    #pragma unroll 8
    for (int c = 0; c < C0; ++c)
        acc = fmaf(xr[c], Wr[c * HEADS], acc);

    // y0 table: y[n*8 + h]; y1 table: y[NUM_NODES*8 + n*8 + h]
    const int n = nodeBase + local;
    if (n < num_nodes) y[half * (NUM_NODES * HEADS) + n * HEADS + h] = acc;
}

__global__ __launch_bounds__(256) void edge_out_kernel(
    const float* __restrict__ y, const float* __restrict__ x1,
    const int* __restrict__ adj, float* __restrict__ out, int E)
{
    const int b      = blockIdx.x;
    const int within = b & 63;            // spreads head blocks across XCDs
    const int group  = b >> 6;            // 32 groups
    const int tid    = threadIdx.x;

    f4v* __restrict__ outv = (f4v*)out;               // 18 f4 per edge row

    if (within < 8) {
        // ---- HEAD role: 256 blocks, gather + relu, 32B stores per edge ----
        const int rank = group * 8 + within;           // 0..255
        const f4v* __restrict__ y0v = (const f4v*)y;            // 2 f4/node
        const f4v* __restrict__ y1v = y0v + 2 * NUM_NODES;

        for (int e = rank * 256 + tid; e < E; e += HEAD_BLOCKS * 256) {
            const int s = adj[e];
            const int t = adj[E + e];
            const f4v a0 = y0v[s * 2];
            const f4v a1 = y0v[s * 2 + 1];
            const f4v b0 = y1v[t * 2];
            const f4v b1 = y1v[t * 2 + 1];
            f4v h0, h1;
            h0.x = fmaxf(a0.x + b0.x, 0.f);
            h0.y = fmaxf(a0.y + b0.y, 0.f);
            h0.z = fmaxf(a0.z + b0.z, 0.f);
            h0.w = fmaxf(a0.w + b0.w, 0.f);
            h1.x = fmaxf(a1.x + b1.x, 0.f);
            h1.y = fmaxf(a1.y + b1.y, 0.f);
            h1.z = fmaxf(a1.z + b1.z, 0.f);
            h1.w = fmaxf(a1.w + b1.w, 0.f);
            __builtin_nontemporal_store(h0, &outv[e * 18]);
            __builtin_nontemporal_store(h1, &outv[e * 18 + 1]);
        }
    } else {
        // ---- COPY role: 1792 blocks, pure streaming x1 -> out[:, 8:] ----
        const int rank = group * 56 + (within - 8);    // 0..1791
        const f4v* __restrict__ x1v = (const f4v*)x1;  // 16 f4/edge
        const int total = E * 16;                      // 10,000,000 f4

        for (int i = rank * 256 + tid; i < total; i += COPY_BLOCKS * 256) {
            const f4v v = x1v[i];
            const int e = i >> 4;
            const int j = i & 15;
            __builtin_nontemporal_store(v, &outv[e * 18 + 2 + j]);
        }
    }
}

extern "C" void kernel_launch(void* const* d_in, const int* in_sizes, int n_in,
                              void* d_out, int out_size, void* d_ws, size_t ws_size,
                              hipStream_t stream) {
    const float* x0  = (const float*)d_in[0];
    const int*   adj = (const int*)d_in[1];   // JAX demotes int64->int32
    const float* x1  = (const float*)d_in[2];
    const float* W   = (const float*)d_in[3];
    float* out = (float*)d_out;
    float* y   = (float*)d_ws;                // 2 * 50000*8 floats = 3.2 MB

    const int E = in_sizes[1] / 2;            // 625000

    {
        dim3 grid((NUM_NODES + NODES_PER_BLK - 1) / NODES_PER_BLK);
        node_proj_kernel<<<grid, 256, 0, stream>>>(x0, W, y, NUM_NODES);
    }
    {
        edge_out_kernel<<<TOTAL_BLOCKS, 256, 0, stream>>>(y, x1, adj, out, E);
    }
}

// Round 5
// 109.849 us; speedup vs baseline: 1.5169x; 1.5169x over previous
//
#include <hip/hip_runtime.h>
#include <hip/hip_bf16.h>

// MultiHeadLiftLayer:
//   y0 = x0 @ W[:128]  (per-node, 50000x8)   -> table in d_ws
//   y1 = x0 @ W[128:]  (per-node, 50000x8)   -> table in d_ws (offset)
//   out[e, 0:8]  = relu(y0[src[e]] + y1[tgt[e]])
//   out[e, 8:72] = x_1[e]                     // (625000, 72) f32
//
// Edge kernel: double-buffered pipelined tiles (T14 async-split pattern).
//   per iteration: issue next tile's adj+y gather loads into regs (latency
//   hides under the stream), stream current tile (LDS heads + x1 -> out,
//   fully contiguous stores, every 128B line written by this block only),
//   compute+write next heads into the other LDS buffer, one barrier.
// NO nontemporal stores: R4 showed nt + partial/split lines => HBM RMW, 2x slower.

typedef float f4v __attribute__((ext_vector_type(4)));

#define NUM_NODES 50000
#define C0 128
#define HEADS 8
#define NODES_PER_BLK 16
#define XS_STRIDE 132            // 128 + 4 pad
#define TILE 256                 // edges per tile
#define EGRID 1024               // edge-kernel blocks (4/CU, 16 waves/CU)

__global__ __launch_bounds__(256) void node_proj_kernel(
    const float* __restrict__ x0, const float* __restrict__ W,
    float* __restrict__ y, int num_nodes)
{
    __shared__ float Ws[2 * C0 * HEADS];          // 8 KB
    __shared__ float xs[NODES_PER_BLK * XS_STRIDE];

    for (int i = threadIdx.x; i < 2 * C0 * HEADS; i += 256) Ws[i] = W[i];

    const int nodeBase = blockIdx.x * NODES_PER_BLK;
    for (int i = threadIdx.x; i < NODES_PER_BLK * C0; i += 256) {
        int r = i >> 7;
        int c = i & (C0 - 1);
        int n = nodeBase + r;
        xs[r * XS_STRIDE + c] = (n < num_nodes) ? x0[n * C0 + c] : 0.f;
    }
    __syncthreads();

    const int local = threadIdx.x >> 4;
    const int slot  = threadIdx.x & 15;   // half*8 + h
    const int half  = slot >> 3;
    const int h     = slot & 7;

    const float* xr = &xs[local * XS_STRIDE];
    const float* Wr = &Ws[half * C0 * HEADS + h];

    float acc = 0.f;
    #pragma unroll 8
    for (int c = 0; c < C0; ++c)
        acc = fmaf(xr[c], Wr[c * HEADS], acc);

    // y0 table: y[n*8 + h]; y1 table: y[NUM_NODES*8 + n*8 + h]
    const int n = nodeBase + local;
    if (n < num_nodes) y[half * (NUM_NODES * HEADS) + n * HEADS + h] = acc;
}

static __device__ __forceinline__ f4v relu4(f4v a, f4v b) {
    f4v r;
    r.x = fmaxf(a.x + b.x, 0.f);
    r.y = fmaxf(a.y + b.y, 0.f);
    r.z = fmaxf(a.z + b.z, 0.f);
    r.w = fmaxf(a.w + b.w, 0.f);
    return r;
}

__global__ __launch_bounds__(256) void edge_out_kernel(
    const float* __restrict__ y, const float* __restrict__ x1,
    const int* __restrict__ adj, float* __restrict__ out, int E, int ntiles)
{
    __shared__ f4v head[2][TILE][2];     // 16 KB

    const int tid = threadIdx.x;
    const f4v* __restrict__ y0v = (const f4v*)y;           // 2 f4 per node
    const f4v* __restrict__ y1v = y0v + 2 * NUM_NODES;
    const f4v* __restrict__ x1v = (const f4v*)x1;          // 16 f4 per edge
    f4v* __restrict__ outv = (f4v*)out;                    // 18 f4 per edge

    // Prologue: gather + compute heads for this block's first tile.
    {
        const int e = blockIdx.x * TILE + tid;
        f4v h0 = {0.f, 0.f, 0.f, 0.f}, h1 = {0.f, 0.f, 0.f, 0.f};
        if (e < E) {
            const int s = adj[e];
            const int t = adj[E + e];
            h0 = relu4(y0v[s * 2],     y1v[t * 2]);
            h1 = relu4(y0v[s * 2 + 1], y1v[t * 2 + 1]);
        }
        head[0][tid][0] = h0;
        head[0][tid][1] = h1;
    }
    __syncthreads();

    int buf = 0;
    for (int t = blockIdx.x; t < ntiles; t += EGRID) {
        const int tn = t + EGRID;

        // Issue next tile's gather loads NOW (complete under the stream below).
        f4v a0, a1, b0, b1;
        bool v2 = false;
        if (tn < ntiles) {
            const int e = tn * TILE + tid;
            v2 = (e < E);
            if (v2) {
                const int s  = adj[e];
                const int tt = adj[E + e];
                a0 = y0v[s * 2];
                a1 = y0v[s * 2 + 1];
                b0 = y1v[tt * 2];
                b1 = y1v[tt * 2 + 1];
            }
        }

        // Stream current tile: fully contiguous stores over [base*18, base*18+n4).
        const int base  = t * TILE;
        const int nrows = (E - base < TILE) ? (E - base) : TILE;
        const int n4    = nrows * 18;
        const f4v* __restrict__ x1b  = x1v  + (size_t)base * 16;
        f4v* __restrict__       outb = outv + (size_t)base * 18;
        #pragma unroll 6
        for (int i = tid; i < n4; i += 256) {
            const int el = i / 18;                 // magic-mul
            const int j  = i - el * 18;
            const f4v v = (j >= 2) ? x1b[el * 16 + (j - 2)] : head[buf][el][j];
            outb[i] = v;
        }

        // Finish next tile's heads into the other buffer.
        if (tn < ntiles) {
            f4v h0 = {0.f, 0.f, 0.f, 0.f}, h1 = {0.f, 0.f, 0.f, 0.f};
            if (v2) { h0 = relu4(a0, b0); h1 = relu4(a1, b1); }
            head[buf ^ 1][tid][0] = h0;
            head[buf ^ 1][tid][1] = h1;
        }
        __syncthreads();   // uniform; separates this write from next stream's reads
        buf ^= 1;
    }
}

extern "C" void kernel_launch(void* const* d_in, const int* in_sizes, int n_in,
                              void* d_out, int out_size, void* d_ws, size_t ws_size,
                              hipStream_t stream) {
    const float* x0  = (const float*)d_in[0];
    const int*   adj = (const int*)d_in[1];   // JAX demotes int64->int32
    const float* x1  = (const float*)d_in[2];
    const float* W   = (const float*)d_in[3];
    float* out = (float*)d_out;
    float* y   = (float*)d_ws;                // 2 * 50000*8 floats = 3.2 MB

    const int E = in_sizes[1] / 2;            // 625000
    const int ntiles = (E + TILE - 1) / TILE; // 2442

    {
        dim3 grid((NUM_NODES + NODES_PER_BLK - 1) / NODES_PER_BLK);
        node_proj_kernel<<<grid, 256, 0, stream>>>(x0, W, y, NUM_NODES);
    }
    {
        edge_out_kernel<<<EGRID, 256, 0, stream>>>(y, x1, adj, out, E, ntiles);
    }
}